// Round 1
// 6856.567 us; speedup vs baseline: 2.6709x; 2.6709x over previous
//
#include <hip/hip_runtime.h>
#include <hip/hip_bf16.h>

typedef unsigned short u16;
typedef short s8v __attribute__((ext_vector_type(8)));   // 8 bf16 in 4 VGPRs
typedef float f4v __attribute__((ext_vector_type(4)));   // MFMA accumulator

#define T_STEPS 128
#define BATCH 32

__device__ __forceinline__ float bf2f(u16 h) { return __uint_as_float(((unsigned)h) << 16); }
__device__ __forceinline__ u16 f2bf(float f) {
    unsigned u = __float_as_uint(f);
    unsigned r = u + 0x7fffu + ((u >> 16) & 1u);
    return (u16)(r >> 16);
}
__device__ __forceinline__ f4v mfma16(s8v a, s8v b, f4v c) {
    return __builtin_amdgcn_mfma_f32_16x16x32_bf16(a, b, c, 0, 0, 0);
}
__device__ __forceinline__ float sigm(float x) { return 1.f / (1.f + __expf(-x)); }
__device__ __forceinline__ float tanhx(float x) { return 1.f - 2.f / (1.f + __expf(2.f * x)); }

// ---------------------------------------------------------------------------
// prep: embedding gathers + bf16 weight packing (unchanged)
// ---------------------------------------------------------------------------
__global__ __launch_bounds__(256) void prep_kernel(
    const int* __restrict__ pos, const int* __restrict__ word,
    const float* __restrict__ pos_emb, const float* __restrict__ word_emb,
    const float* __restrict__ pWih, const float* __restrict__ pWhh,
    const float* __restrict__ w0Wih, const float* __restrict__ w0Whh,
    const float* __restrict__ w1Wih, const float* __restrict__ w1Whh,
    const float* __restrict__ wp1W,
    u16* __restrict__ p_emb_bf, u16* __restrict__ w_emb_bf,
    u16* __restrict__ word_emb_bf, u16* __restrict__ wp1W_bf,
    u16* __restrict__ posWihA, u16* __restrict__ w0WihA,
    u16* __restrict__ posW, u16* __restrict__ w0W, u16* __restrict__ w1W)
{
    const long long total = 36372480LL;
    for (long long i = (long long)blockIdx.x * 256 + threadIdx.x; i < total;
         i += (long long)gridDim.x * 256) {
        long long r = i;
        if (r < 262144) { int tb = (int)(r >> 6), e = (int)(r & 63);
            p_emb_bf[r] = f2bf(pos_emb[(size_t)pos[tb] * 64 + e]); continue; }
        r -= 262144;
        if (r < 2097152) { int tb = (int)(r >> 9), e = (int)(r & 511);
            w_emb_bf[r] = f2bf(word_emb[(size_t)word[tb] * 512 + e]); continue; }
        r -= 2097152;
        if (r < 16384000) { word_emb_bf[r] = f2bf(word_emb[r]); continue; }
        r -= 16384000;
        if (r < 524288) { wp1W_bf[r] = f2bf(wp1W[r]); continue; }
        r -= 524288;
        if (r < 65536) { int j = (int)(r >> 6), k = (int)(r & 63);
            posWihA[r] = f2bf(pWih[(size_t)j * 1088 + k]); continue; }
        r -= 65536;
        if (r < 2097152) { int j = (int)(r >> 9), k = (int)(r & 511);
            w0WihA[r] = f2bf(w0Wih[(size_t)j * 768 + k]); continue; }
        r -= 2097152;
        if (r < 1310720) { int j = (int)(r / 1280), c = (int)(r % 1280);
            posW[r] = f2bf(c < 1024 ? pWih[(size_t)j * 1088 + 64 + c]
                                    : pWhh[(size_t)j * 256 + (c - 1024)]); continue; }
        r -= 1310720;
        if (r < 5242880) { int j = (int)(r / 1280), c = (int)(r % 1280);
            w0W[r] = f2bf(c < 256 ? w0Wih[(size_t)j * 768 + 512 + c]
                                  : w0Whh[(size_t)j * 1024 + (c - 256)]); continue; }
        r -= 5242880;
        { int j = (int)(r >> 11), c = (int)(r & 2047);
          w1W[r] = f2bf(c < 1024 ? w1Wih[(size_t)j * 1024 + c]
                                 : w1Whh[(size_t)j * 1024 + (c - 1024)]); }
    }
}

// ---------------------------------------------------------------------------
// Generic bf16 GEMM (unchanged)
// ---------------------------------------------------------------------------
__global__ __launch_bounds__(256) void gemm_bf16_kernel(
    const u16* __restrict__ A, const u16* __restrict__ B,
    const float* __restrict__ bias1, const float* __restrict__ bias2,
    u16* __restrict__ out, int M, int N, int K)
{
    const int tid = threadIdx.x, w = tid >> 6, lane = tid & 63;
    const int quad = lane >> 4, lm = lane & 15;
    const int n0 = blockIdx.x * 64, m0 = blockIdx.y * 64 + w * 16;
    const u16* Ap = A + (size_t)(m0 + lm) * K + quad * 8;
    const u16* Bp = B + (size_t)(n0 + lm) * K + quad * 8;
    f4v acc[4] = {{0,0,0,0},{0,0,0,0},{0,0,0,0},{0,0,0,0}};
    for (int k = 0; k < K; k += 32) {
        s8v a = *(const s8v*)(Ap + k);
#pragma unroll
        for (int nt = 0; nt < 4; nt++) {
            s8v b = *(const s8v*)(Bp + (size_t)nt * 16 * K + k);
            acc[nt] = mfma16(a, b, acc[nt]);
        }
    }
#pragma unroll
    for (int nt = 0; nt < 4; nt++)
#pragma unroll
        for (int r = 0; r < 4; r++) {
            int col = n0 + nt * 16 + lm;
            int row = m0 + quad * 4 + r;
            float v = acc[nt][r];
            if (bias1) v += bias1[col];
            if (bias2) v += bias2[col];
            out[(size_t)row * N + col] = f2bf(v);
        }
}

// ---------------------------------------------------------------------------
// Persistent recurrence kernel, v2.
// 144 WGs x 512 threads (8 waves): wave w -> gate g=w&3, K-half kh=w>>2.
//  blk 0..15  : pos cell (H=256,  x1=wh1 K=1024, x2=ph  K=256,  rs=1280)
//  blk 16..79 : w0 cell  (H=1024, x1=ph  K=256,  x2=wh0 K=1024, rs=1280)
//  blk 80..143: w1 cell  (H=1024, x1=wh0 K=1024, x2=wh1 K=1024, rs=2048)
// Two-phase: phase A (own-history x2 part, gated on OWN cell's flag t-1,
// ~3 stages off the critical path) runs before the producer wait; phase B
// (the just-produced x1 part) is the only GEMM on the critical path.
// Phase-B weights + elementwise inputs are prefetched into registers before
// the producer spin so their L3 latency hides under the wait.
// ---------------------------------------------------------------------------
__device__ __forceinline__ void waitflag(int* p, int target) {
    // relaxed spin: polls must NOT emit buffer_inv (the acquire-spin version
    // invalidates the shared XCD L2 every ~64 cycles from ~90 idle WGs,
    // evicting the working cell's weights). One acquire fence at the end.
    while (__hip_atomic_load(p, __ATOMIC_RELAXED, __HIP_MEMORY_SCOPE_AGENT) < target)
        __builtin_amdgcn_s_sleep(1);
    __builtin_amdgcn_fence(__ATOMIC_ACQUIRE, "agent");
}

template<int CELL, int HH, int L1, int L2, int RS>
__device__ __forceinline__ void recur_cell(
    const u16* __restrict__ W, const u16* __restrict__ IH,
    const float* __restrict__ bih, const float* __restrict__ bhh,
    const u16* __restrict__ x1base, const u16* __restrict__ x2base,
    u16* __restrict__ hbase, float* __restrict__ cbuf,
    int* f_self, int self_tgt, int* f_prod, int prod_tgt,
    int n0, float (&lds_g)[8][32][16])
{
    const int tid = threadIdx.x, w = tid >> 6, lane = tid & 63;
    const int quad = lane >> 4, lm = lane & 15, g = w & 3, kh = w >> 2;
    constexpr int NA  = L2 / 64;              // per-wave k-iters, phase A
    constexpr int NB  = L1 / 64;              // per-wave k-iters, phase B
    constexpr int NBP = (NB < 8) ? NB : 8;    // B-weight regs (VGPR cap)
    const int row = g * HH + n0 + lm;
    const u16* WpB = W + (size_t)row * RS + quad * 8 + kh * (L1 / 2);
    const u16* WpA = W + (size_t)row * RS + quad * 8 + L1 + kh * (L2 / 2);
    const int eb = tid >> 4, eu = tid & 15, ecol = n0 + eu;   // elementwise elem

    for (int t = 0; t < T_STEPS; t++) {
        // 1. prefetch phase-B weight fragments (addresses flag-independent;
        //    values constant, so racing the later invalidate is harmless)
        s8v wb[NBP];
#pragma unroll
        for (int i = 0; i < NBP; i++) wb[i] = *(const s8v*)(WpB + i * 32);

        // 2. A-wait: own cell, step t-1 (normally already satisfied)
        if (t > 0 && tid == 0) waitflag(f_self + t - 1, self_tgt);
        __syncthreads();

        // 3. phase A: own-history GEMM part (off critical path)
        f4v am0 = {0,0,0,0}, am1 = {0,0,0,0};
        {
            const u16* xa = x2base + (size_t)t * 32 * L2
                          + (size_t)lm * L2 + quad * 8 + kh * (L2 / 2);
            const u16* xb = xa + (size_t)16 * L2;
#pragma unroll 4
            for (int i = 0; i < NA; i++) {
                s8v b  = *(const s8v*)(WpA + i * 32);
                s8v a0 = *(const s8v*)(xa + i * 32);
                s8v a1 = *(const s8v*)(xb + i * 32);
                am0 = mfma16(a0, b, am0);
                am1 = mfma16(a1, b, am1);
            }
        }

        // 4. prefetch elementwise inputs (IH stream / biases, own c-state)
        float ih0, ih1, ih2, ih3;
        if constexpr (CELL == 0) {
            const u16* ih = IH + (size_t)(t * 32 + eb) * 1024 + ecol;
            ih0 = bf2f(ih[0]);   ih1 = bf2f(ih[256]);
            ih2 = bf2f(ih[512]); ih3 = bf2f(ih[768]);
        } else if constexpr (CELL == 1) {
            const u16* ih = IH + (size_t)(t * 32 + eb) * 4096 + ecol;
            ih0 = bf2f(ih[0]);    ih1 = bf2f(ih[1024]);
            ih2 = bf2f(ih[2048]); ih3 = bf2f(ih[3072]);
        } else {
            ih0 = bih[ecol]        + bhh[ecol];
            ih1 = bih[1024 + ecol] + bhh[1024 + ecol];
            ih2 = bih[2048 + ecol] + bhh[2048 + ecol];
            ih3 = bih[3072 + ecol] + bhh[3072 + ecol];
        }
        float cold = cbuf[eb * HH + ecol];

        // 5. B-wait: direct producer (THE critical-path wait)
        if (tid == 0 && !(CELL == 0 && t == 0))
            waitflag(f_prod + (CELL == 0 ? t - 1 : t), prod_tgt);
        __syncthreads();

        // 6. phase B: just-produced input GEMM part
        {
            const int t1 = (CELL == 0) ? t : t + 1;
            const u16* xa = x1base + (size_t)t1 * 32 * L1
                          + (size_t)lm * L1 + quad * 8 + kh * (L1 / 2);
            const u16* xb = xa + (size_t)16 * L1;
#pragma unroll
            for (int i = 0; i < NBP; i++) {       // full unroll: wb const-indexed
                s8v a0 = *(const s8v*)(xa + i * 32);
                s8v a1 = *(const s8v*)(xb + i * 32);
                am0 = mfma16(a0, wb[i], am0);
                am1 = mfma16(a1, wb[i], am1);
            }
            if constexpr (NB > NBP) {
#pragma unroll 4
                for (int i = NBP; i < NB; i++) {  // streamed tail
                    s8v b  = *(const s8v*)(WpB + i * 32);
                    s8v a0 = *(const s8v*)(xa + i * 32);
                    s8v a1 = *(const s8v*)(xb + i * 32);
                    am0 = mfma16(a0, b, am0);
                    am1 = mfma16(a1, b, am1);
                }
            }
        }

        // 7. gate partials -> LDS (wave w = gate g, half kh)
#pragma unroll
        for (int r = 0; r < 4; r++) {
            lds_g[w][quad * 4 + r][lm]      = am0[r];
            lds_g[w][16 + quad * 4 + r][lm] = am1[r];
        }
        __syncthreads();

        // 8. elementwise LSTM update: one (batch, col) element per thread
        {
            float gi = lds_g[0][eb][eu] + lds_g[4][eb][eu] + ih0;
            float gf = lds_g[1][eb][eu] + lds_g[5][eb][eu] + ih1;
            float gg = lds_g[2][eb][eu] + lds_g[6][eb][eu] + ih2;
            float go = lds_g[3][eb][eu] + lds_g[7][eb][eu] + ih3;
            float c2 = sigm(gf) * cold + sigm(gi) * tanhx(gg);
            float h2 = sigm(go) * tanhx(c2);
            cbuf[eb * HH + ecol] = c2;
            hbase[(size_t)(t + 1) * 32 * HH + (size_t)eb * HH + ecol] = f2bf(h2);
        }
        __syncthreads();
        if (tid == 0) { __threadfence(); atomicAdd(f_self + t, 1); }
    }
}

__global__ __launch_bounds__(512, 4) void recur_kernel(
    const u16* __restrict__ posW, const u16* __restrict__ w0W, const u16* __restrict__ w1W,
    const u16* __restrict__ posIH, const u16* __restrict__ w0IH,
    const float* __restrict__ w1bih, const float* __restrict__ w1bhh,
    u16* __restrict__ ph, u16* __restrict__ wh0, u16* __restrict__ wh1,
    float* __restrict__ c_pos, float* __restrict__ c_w0, float* __restrict__ c_w1,
    int* flags)
{
    __shared__ float lds_g[8][32][16];
    int* f_pos = flags; int* f_w0 = flags + 128; int* f_w1 = flags + 256;
    const int blk = blockIdx.x;
    if (blk < 16)
        recur_cell<0, 256, 1024, 256, 1280>(posW, posIH, nullptr, nullptr,
            wh1, ph, ph, c_pos, f_pos, 16, f_w1, 64, blk * 16, lds_g);
    else if (blk < 80)
        recur_cell<1, 1024, 256, 1024, 1280>(w0W, w0IH, nullptr, nullptr,
            ph, wh0, wh0, c_w0, f_w0, 64, f_pos, 16, (blk - 16) * 16, lds_g);
    else
        recur_cell<2, 1024, 1024, 1024, 2048>(w1W, nullptr, w1bih, w1bhh,
            wh0, wh1, wh1, c_w1, f_w1, 64, f_w0, 64, (blk - 80) * 16, lds_g);
}

// ---------------------------------------------------------------------------
// pos projection + log-softmax over 45 (unchanged)
// ---------------------------------------------------------------------------
__global__ __launch_bounds__(256) void posproj_kernel(
    const u16* __restrict__ ph, const float* __restrict__ W,
    const float* __restrict__ bias, float* __restrict__ out)
{
    __shared__ float w_lds[256 * 48 + 32];
    for (int i = threadIdx.x; i < 45 * 256; i += 256) {
        int j = i >> 8, k = i & 255;
        w_lds[k * 48 + j] = W[i];
    }
    __syncthreads();
    const int wv = threadIdx.x >> 6, lane = threadIdx.x & 63;
    const int row = blockIdx.x * 4 + wv;
    const int t = row >> 5, b = row & 31;
    const u16* x = ph + (size_t)(t + 1) * 8192 + b * 256;
    const int j = (lane < 45) ? lane : 0;
    float acc = 0.f;
    for (int k = 0; k < 256; k++) acc += bf2f(x[k]) * w_lds[k * 48 + j];
    float l = (lane < 45) ? (acc + bias[j]) : -INFINITY;
    float m = l;
    for (int mask = 1; mask < 64; mask <<= 1) m = fmaxf(m, __shfl_xor(m, mask));
    float e = (lane < 45) ? __expf(l - m) : 0.f;
    float s = e;
    for (int mask = 1; mask < 64; mask <<= 1) s += __shfl_xor(s, mask);
    if (lane < 45) out[(size_t)row * 45 + lane] = l - m - logf(s);
}

// ---------------------------------------------------------------------------
// word projection (unchanged)
// ---------------------------------------------------------------------------
__global__ __launch_bounds__(256) void wordproj_kernel(
    const u16* __restrict__ A, const u16* __restrict__ B,
    const float* __restrict__ bias, float* __restrict__ out,
    float* __restrict__ sumexp, int M, int N, int K)
{
    const int tid = threadIdx.x, w = tid >> 6, lane = tid & 63;
    const int quad = lane >> 4, lm = lane & 15;
    const int n0 = blockIdx.x * 64, m0 = blockIdx.y * 64 + w * 16;
    const u16* Ap = A + (size_t)(m0 + lm) * K + quad * 8;
    const u16* Bp = B + (size_t)(n0 + lm) * K + quad * 8;
    f4v acc[4] = {{0,0,0,0},{0,0,0,0},{0,0,0,0},{0,0,0,0}};
    for (int k = 0; k < K; k += 32) {
        s8v a = *(const s8v*)(Ap + k);
#pragma unroll
        for (int nt = 0; nt < 4; nt++) {
            s8v b = *(const s8v*)(Bp + (size_t)nt * 16 * K + k);
            acc[nt] = mfma16(a, b, acc[nt]);
        }
    }
    float se[4] = {0.f, 0.f, 0.f, 0.f};
#pragma unroll
    for (int nt = 0; nt < 4; nt++)
#pragma unroll
        for (int r = 0; r < 4; r++) {
            int col = n0 + nt * 16 + lm;
            int row = m0 + quad * 4 + r;
            float v = acc[nt][r] + bias[col];
            out[(size_t)row * N + col] = v;
            se[r] += __expf(v);
        }
#pragma unroll
    for (int r = 0; r < 4; r++) {
        float s = se[r];
        s += __shfl_xor(s, 1); s += __shfl_xor(s, 2);
        s += __shfl_xor(s, 4); s += __shfl_xor(s, 8);
        if (lm == 0) atomicAdd(&sumexp[m0 + quad * 4 + r], s);
    }
}

__global__ __launch_bounds__(256) void fixup_kernel(
    float* __restrict__ wout, const float* __restrict__ sumexp)
{
    const int row = blockIdx.x;
    const float lse = logf(sumexp[row]);
    float4* p = (float4*)(wout + (size_t)row * 32000);
    for (int i = threadIdx.x; i < 8000; i += 256) {
        float4 v = p[i];
        v.x -= lse; v.y -= lse; v.z -= lse; v.w -= lse;
        p[i] = v;
    }
}

__global__ __launch_bounds__(256) void fallback_zero(float* out, long long n) {
    for (long long i = (long long)blockIdx.x * 256 + threadIdx.x; i < n;
         i += (long long)gridDim.x * 256) out[i] = 0.f;
}

// ---------------------------------------------------------------------------
extern "C" void kernel_launch(void* const* d_in, const int* in_sizes, int n_in,
                              void* d_out, int out_size, void* d_ws, size_t ws_size,
                              hipStream_t stream)
{
    const int*   pos      = (const int*)  d_in[0];
    const int*   word     = (const int*)  d_in[1];
    const float* pos_emb  = (const float*)d_in[2];
    const float* word_emb = (const float*)d_in[3];
    const float* pWih     = (const float*)d_in[4];
    const float* pWhh     = (const float*)d_in[5];
    const float* pbih     = (const float*)d_in[6];
    const float* pbhh     = (const float*)d_in[7];
    const float* w0Wih    = (const float*)d_in[8];
    const float* w0Whh    = (const float*)d_in[9];
    const float* w0bih    = (const float*)d_in[10];
    const float* w0bhh    = (const float*)d_in[11];
    const float* w1Wih    = (const float*)d_in[12];
    const float* w1Whh    = (const float*)d_in[13];
    const float* w1bih    = (const float*)d_in[14];
    const float* w1bhh    = (const float*)d_in[15];
    const float* ppW      = (const float*)d_in[16];
    const float* ppb      = (const float*)d_in[17];
    const float* wp1W     = (const float*)d_in[18];
    const float* wp1b     = (const float*)d_in[19];
    const float* wp2b     = (const float*)d_in[20];

    char* ws = (char*)d_ws;
    size_t off = 0;
    auto alloc = [&](size_t bytes) -> size_t {
        size_t o = off; off = (off + bytes + 255) & ~(size_t)255; return o;
    };
    // --- zero-init region (one memset) ---
    size_t o_flags  = alloc(384 * 4);
    size_t o_sumexp = alloc(4096 * 4);
    size_t o_cpos   = alloc(32 * 256 * 4);
    size_t o_cw0    = alloc(32 * 1024 * 4);
    size_t o_cw1    = alloc(32 * 1024 * 4);
    size_t o_ph     = alloc((size_t)129 * 32 * 256 * 2);
    size_t o_wh0    = alloc((size_t)129 * 32 * 1024 * 2);
    size_t o_wh1    = alloc((size_t)129 * 32 * 1024 * 2);
    size_t zero_end = off;
    // --- rest ---
    size_t o_pemb   = alloc((size_t)4096 * 64 * 2);
    size_t o_wemb   = alloc((size_t)4096 * 512 * 2);
    size_t o_wembW  = alloc((size_t)32000 * 512 * 2);
    size_t o_wp1    = alloc((size_t)512 * 1024 * 2);
    size_t o_pWihA  = alloc((size_t)1024 * 64 * 2);
    size_t o_w0WihA = alloc((size_t)4096 * 512 * 2);
    size_t o_posW   = alloc((size_t)1024 * 1280 * 2);
    size_t o_w0W    = alloc((size_t)4096 * 1280 * 2);
    size_t o_w1W    = alloc((size_t)4096 * 2048 * 2);
    size_t o_posIH  = alloc((size_t)4096 * 1024 * 2);
    size_t o_w0IH   = alloc((size_t)4096 * 4096 * 2);
    size_t o_wmid   = alloc((size_t)4096 * 512 * 2);

    if (ws_size < off) {
        fallback_zero<<<2048, 256, 0, stream>>>((float*)d_out, (long long)out_size);
        return;
    }

    hipMemsetAsync(ws, 0, zero_end, stream);

    prep_kernel<<<2048, 256, 0, stream>>>(
        pos, word, pos_emb, word_emb, pWih, pWhh, w0Wih, w0Whh, w1Wih, w1Whh, wp1W,
        (u16*)(ws + o_pemb), (u16*)(ws + o_wemb), (u16*)(ws + o_wembW), (u16*)(ws + o_wp1),
        (u16*)(ws + o_pWihA), (u16*)(ws + o_w0WihA),
        (u16*)(ws + o_posW), (u16*)(ws + o_w0W), (u16*)(ws + o_w1W));

    // posIH = p_emb @ posWihA^T + pbih + pbhh   [4096,1024]
    gemm_bf16_kernel<<<dim3(16, 64), 256, 0, stream>>>(
        (u16*)(ws + o_pemb), (u16*)(ws + o_pWihA), pbih, pbhh,
        (u16*)(ws + o_posIH), 4096, 1024, 64);
    // w0IH = w_emb @ w0WihA^T + w0bih + w0bhh   [4096,4096]
    gemm_bf16_kernel<<<dim3(64, 64), 256, 0, stream>>>(
        (u16*)(ws + o_wemb), (u16*)(ws + o_w0WihA), w0bih, w0bhh,
        (u16*)(ws + o_w0IH), 4096, 4096, 512);

    recur_kernel<<<144, 512, 0, stream>>>(
        (u16*)(ws + o_posW), (u16*)(ws + o_w0W), (u16*)(ws + o_w1W),
        (u16*)(ws + o_posIH), (u16*)(ws + o_w0IH), w1bih, w1bhh,
        (u16*)(ws + o_ph), (u16*)(ws + o_wh0), (u16*)(ws + o_wh1),
        (float*)(ws + o_cpos), (float*)(ws + o_cw0), (float*)(ws + o_cw1),
        (int*)(ws + o_flags));

    // w_mid = wh1[1..128] @ wp1W^T + wp1b   [4096,512] bf16
    gemm_bf16_kernel<<<dim3(8, 64), 256, 0, stream>>>(
        (u16*)(ws + o_wh1) + 32 * 1024, (u16*)(ws + o_wp1), wp1b, nullptr,
        (u16*)(ws + o_wmid), 4096, 512, 1024);

    posproj_kernel<<<1024, 256, 0, stream>>>(
        (u16*)(ws + o_ph), ppW, ppb, (float*)d_out);

    wordproj_kernel<<<dim3(500, 64), 256, 0, stream>>>(
        (u16*)(ws + o_wmid), (u16*)(ws + o_wembW), wp2b,
        (float*)d_out + 184320, (float*)(ws + o_sumexp), 4096, 32000, 512);

    fixup_kernel<<<4096, 256, 0, stream>>>(
        (float*)d_out + 184320, (float*)(ws + o_sumexp));
}

// Round 3
// 6621.723 us; speedup vs baseline: 2.7656x; 1.0355x over previous
//
#include <hip/hip_runtime.h>
#include <hip/hip_bf16.h>

typedef unsigned short u16;
typedef short s8v __attribute__((ext_vector_type(8)));   // 8 bf16 in 4 VGPRs
typedef float f4v __attribute__((ext_vector_type(4)));   // MFMA accumulator

#define T_STEPS 128
#define BATCH 32

__device__ __forceinline__ float bf2f(u16 h) { return __uint_as_float(((unsigned)h) << 16); }
__device__ __forceinline__ u16 f2bf(float f) {
    unsigned u = __float_as_uint(f);
    unsigned r = u + 0x7fffu + ((u >> 16) & 1u);
    return (u16)(r >> 16);
}
__device__ __forceinline__ f4v mfma16(s8v a, s8v b, f4v c) {
    return __builtin_amdgcn_mfma_f32_16x16x32_bf16(a, b, c, 0, 0, 0);
}
__device__ __forceinline__ float sigm(float x) { return 1.f / (1.f + __expf(-x)); }
__device__ __forceinline__ float tanhx(float x) { return 1.f - 2.f / (1.f + __expf(2.f * x)); }

// ---------------------------------------------------------------------------
// prep: embedding gathers + bf16 weight packing (unchanged)
// ---------------------------------------------------------------------------
__global__ __launch_bounds__(256) void prep_kernel(
    const int* __restrict__ pos, const int* __restrict__ word,
    const float* __restrict__ pos_emb, const float* __restrict__ word_emb,
    const float* __restrict__ pWih, const float* __restrict__ pWhh,
    const float* __restrict__ w0Wih, const float* __restrict__ w0Whh,
    const float* __restrict__ w1Wih, const float* __restrict__ w1Whh,
    const float* __restrict__ wp1W,
    u16* __restrict__ p_emb_bf, u16* __restrict__ w_emb_bf,
    u16* __restrict__ word_emb_bf, u16* __restrict__ wp1W_bf,
    u16* __restrict__ posWihA, u16* __restrict__ w0WihA,
    u16* __restrict__ posW, u16* __restrict__ w0W, u16* __restrict__ w1W)
{
    const long long total = 36372480LL;
    for (long long i = (long long)blockIdx.x * 256 + threadIdx.x; i < total;
         i += (long long)gridDim.x * 256) {
        long long r = i;
        if (r < 262144) { int tb = (int)(r >> 6), e = (int)(r & 63);
            p_emb_bf[r] = f2bf(pos_emb[(size_t)pos[tb] * 64 + e]); continue; }
        r -= 262144;
        if (r < 2097152) { int tb = (int)(r >> 9), e = (int)(r & 511);
            w_emb_bf[r] = f2bf(word_emb[(size_t)word[tb] * 512 + e]); continue; }
        r -= 2097152;
        if (r < 16384000) { word_emb_bf[r] = f2bf(word_emb[r]); continue; }
        r -= 16384000;
        if (r < 524288) { wp1W_bf[r] = f2bf(wp1W[r]); continue; }
        r -= 524288;
        if (r < 65536) { int j = (int)(r >> 6), k = (int)(r & 63);
            posWihA[r] = f2bf(pWih[(size_t)j * 1088 + k]); continue; }
        r -= 65536;
        if (r < 2097152) { int j = (int)(r >> 9), k = (int)(r & 511);
            w0WihA[r] = f2bf(w0Wih[(size_t)j * 768 + k]); continue; }
        r -= 2097152;
        if (r < 1310720) { int j = (int)(r / 1280), c = (int)(r % 1280);
            posW[r] = f2bf(c < 1024 ? pWih[(size_t)j * 1088 + 64 + c]
                                    : pWhh[(size_t)j * 256 + (c - 1024)]); continue; }
        r -= 1310720;
        if (r < 5242880) { int j = (int)(r / 1280), c = (int)(r % 1280);
            w0W[r] = f2bf(c < 256 ? w0Wih[(size_t)j * 768 + 512 + c]
                                  : w0Whh[(size_t)j * 1024 + (c - 256)]); continue; }
        r -= 5242880;
        { int j = (int)(r >> 11), c = (int)(r & 2047);
          w1W[r] = f2bf(c < 1024 ? w1Wih[(size_t)j * 1024 + c]
                                 : w1Whh[(size_t)j * 1024 + (c - 1024)]); }
    }
}

// ---------------------------------------------------------------------------
// Generic bf16 GEMM (unchanged)
// ---------------------------------------------------------------------------
__global__ __launch_bounds__(256) void gemm_bf16_kernel(
    const u16* __restrict__ A, const u16* __restrict__ B,
    const float* __restrict__ bias1, const float* __restrict__ bias2,
    u16* __restrict__ out, int M, int N, int K)
{
    const int tid = threadIdx.x, w = tid >> 6, lane = tid & 63;
    const int quad = lane >> 4, lm = lane & 15;
    const int n0 = blockIdx.x * 64, m0 = blockIdx.y * 64 + w * 16;
    const u16* Ap = A + (size_t)(m0 + lm) * K + quad * 8;
    const u16* Bp = B + (size_t)(n0 + lm) * K + quad * 8;
    f4v acc[4] = {{0,0,0,0},{0,0,0,0},{0,0,0,0},{0,0,0,0}};
    for (int k = 0; k < K; k += 32) {
        s8v a = *(const s8v*)(Ap + k);
#pragma unroll
        for (int nt = 0; nt < 4; nt++) {
            s8v b = *(const s8v*)(Bp + (size_t)nt * 16 * K + k);
            acc[nt] = mfma16(a, b, acc[nt]);
        }
    }
#pragma unroll
    for (int nt = 0; nt < 4; nt++)
#pragma unroll
        for (int r = 0; r < 4; r++) {
            int col = n0 + nt * 16 + lm;
            int row = m0 + quad * 4 + r;
            float v = acc[nt][r];
            if (bias1) v += bias1[col];
            if (bias2) v += bias2[col];
            out[(size_t)row * N + col] = f2bf(v);
        }
}

// ---------------------------------------------------------------------------
// Persistent recurrence kernel, v4 (= v3 design, hang-proofed).
//  - No acquire fences / no threadfence in the loop: weights, IH and c-state
//    stay L1/L2-resident for all 128 steps.
//  - h slots are WRITE-ONCE; stored via agent-scope relaxed atomic store
//    (compiler emits the coherent-point write-through), so consumers'
//    ordinary cached reads can never hit a stale line (no cache ever held a
//    slot line before its producer wrote it).
//  - Ordering: h-stores drained (vmcnt 0) -> barrier -> flag atomicAdd (RMW,
//    executes at the coherence point; visibility guaranteed - same primitive
//    as the proven v1/v2 kernels), one slot per producer WG, no contention.
//  - Consumer wave-0 lanes poll one slot each (relaxed loads - proven by v2),
//    with a watchdog escape so any logic error fails fast instead of hanging.
// ---------------------------------------------------------------------------
__device__ __forceinline__ void waitwg(int* f, int n) {
    if (threadIdx.x < 64) {
        int* p = f + (threadIdx.x < (unsigned)n ? threadIdx.x : 0);
        int tries = 0;
        while (__hip_atomic_load(p, __ATOMIC_RELAXED, __HIP_MEMORY_SCOPE_AGENT) == 0) {
            __builtin_amdgcn_s_sleep(1);
            if (++tries > (1 << 19)) break;   // ~15 ms: escape hatch, never hang
        }
    }
    __syncthreads();
    asm volatile("" ::: "memory");   // no load hoisting above the flag wait
}

template<int CELL, int HH, int L1, int L2, int RS>
__device__ __forceinline__ void recur_cell(
    const u16* __restrict__ W, const u16* __restrict__ IH,
    const float* __restrict__ bih, const float* __restrict__ bhh,
    const u16* __restrict__ x1base, const u16* __restrict__ x2base,
    u16* __restrict__ hbase, float* __restrict__ cbuf,
    int* f_self, int nself, int* f_prod, int nprod,
    int tile, float (&lds_g)[8][32][16])
{
    const int tid = threadIdx.x, w = tid >> 6, lane = tid & 63;
    const int quad = lane >> 4, lm = lane & 15, g = w & 3, kh = w >> 2;
    const int n0 = tile * 16;
    constexpr int NA = L2 / 64;   // per-wave k-iters, phase A (half of L2)
    constexpr int NB = L1 / 64;   // per-wave k-iters, phase B (half of L1)
    const int row = g * HH + n0 + lm;
    const u16* WpB = W + (size_t)row * RS + quad * 8 + kh * (L1 / 2);
    const u16* WpA = W + (size_t)row * RS + quad * 8 + L1 + kh * (L2 / 2);
    // elementwise: threads 0..255, 2 adjacent cols each
    const int eb = tid >> 3, ec = (tid & 7) * 2, ecol = n0 + ec;

    // CELL2 gate biases are t-invariant: hoist out of the loop
    float bi0=0, bi1=0, bf0=0, bf1=0, bg0=0, bg1=0, bo0=0, bo1=0;
    if (CELL == 2 && tid < 256) {
        bi0 = bih[ecol]        + bhh[ecol];
        bi1 = bih[ecol+1]      + bhh[ecol+1];
        bf0 = bih[1024+ecol]   + bhh[1024+ecol];
        bf1 = bih[1024+ecol+1] + bhh[1024+ecol+1];
        bg0 = bih[2048+ecol]   + bhh[2048+ecol];
        bg1 = bih[2048+ecol+1] + bhh[2048+ecol+1];
        bo0 = bih[3072+ecol]   + bhh[3072+ecol];
        bo1 = bih[3072+ecol+1] + bhh[3072+ecol+1];
    }

    for (int t = 0; t < T_STEPS; t++) {
        // A-wait: own cell finished step t-1 (normally already satisfied)
        if (t > 0) waitwg(f_self + (t - 1) * 64, nself);

        // phase A: own-history GEMM half (off the critical path)
        f4v am0 = {0,0,0,0}, am1 = {0,0,0,0};
        {
            const u16* xa = x2base + (size_t)t * 32 * L2
                          + (size_t)lm * L2 + quad * 8 + kh * (L2 / 2);
            const u16* xb = xa + (size_t)16 * L2;
#pragma unroll
            for (int i = 0; i < NA; i++) {
                s8v b  = *(const s8v*)(WpA + i * 32);
                s8v a0 = *(const s8v*)(xa + i * 32);
                s8v a1 = *(const s8v*)(xb + i * 32);
                am0 = mfma16(a0, b, am0);
                am1 = mfma16(a1, b, am1);
            }
        }

        // prefetch elementwise inputs (IH gates, c-state) under the wait
        unsigned ihp0=0, ihp1=0, ihp2=0, ihp3=0;
        float2 cold = {0.f, 0.f};
        if (tid < 256) {
            if constexpr (CELL == 0) {
                const u16* ih = IH + (size_t)(t * 32 + eb) * 1024 + ecol;
                ihp0 = *(const unsigned*)(ih);
                ihp1 = *(const unsigned*)(ih + 256);
                ihp2 = *(const unsigned*)(ih + 512);
                ihp3 = *(const unsigned*)(ih + 768);
            } else if constexpr (CELL == 1) {
                const u16* ih = IH + (size_t)(t * 32 + eb) * 4096 + ecol;
                ihp0 = *(const unsigned*)(ih);
                ihp1 = *(const unsigned*)(ih + 1024);
                ihp2 = *(const unsigned*)(ih + 2048);
                ihp3 = *(const unsigned*)(ih + 3072);
            }
            cold = *(const float2*)(cbuf + eb * HH + ecol);
        }
        asm volatile("" ::: "memory");

        // B-wait: direct producer (THE critical-path wait)
        if (!(CELL == 0 && t == 0))
            waitwg(f_prod + (CELL == 0 ? (t - 1) : t) * 64, nprod);

        // phase B: just-produced input GEMM half
        {
            const int t1 = (CELL == 0) ? t : t + 1;
            const u16* xa = x1base + (size_t)t1 * 32 * L1
                          + (size_t)lm * L1 + quad * 8 + kh * (L1 / 2);
            const u16* xb = xa + (size_t)16 * L1;
#pragma unroll
            for (int i = 0; i < NB; i++) {
                s8v b  = *(const s8v*)(WpB + i * 32);
                s8v a0 = *(const s8v*)(xa + i * 32);
                s8v a1 = *(const s8v*)(xb + i * 32);
                am0 = mfma16(a0, b, am0);
                am1 = mfma16(a1, b, am1);
            }
        }

        // gate partials -> LDS (wave w = gate g, K-half kh)
#pragma unroll
        for (int r = 0; r < 4; r++) {
            lds_g[w][quad * 4 + r][lm]      = am0[r];
            lds_g[w][16 + quad * 4 + r][lm] = am1[r];
        }
        __syncthreads();

        // elementwise LSTM update: 2 adjacent (eb, col) elements per thread
        if (tid < 256) {
            float gi0 = lds_g[0][eb][ec]   + lds_g[4][eb][ec];
            float gi1 = lds_g[0][eb][ec+1] + lds_g[4][eb][ec+1];
            float gf0 = lds_g[1][eb][ec]   + lds_g[5][eb][ec];
            float gf1 = lds_g[1][eb][ec+1] + lds_g[5][eb][ec+1];
            float gg0 = lds_g[2][eb][ec]   + lds_g[6][eb][ec];
            float gg1 = lds_g[2][eb][ec+1] + lds_g[6][eb][ec+1];
            float go0 = lds_g[3][eb][ec]   + lds_g[7][eb][ec];
            float go1 = lds_g[3][eb][ec+1] + lds_g[7][eb][ec+1];
            if constexpr (CELL == 2) {
                gi0 += bi0; gi1 += bi1; gf0 += bf0; gf1 += bf1;
                gg0 += bg0; gg1 += bg1; go0 += bo0; go1 += bo1;
            } else {
                gi0 += bf2f((u16)(ihp0 & 0xffff)); gi1 += bf2f((u16)(ihp0 >> 16));
                gf0 += bf2f((u16)(ihp1 & 0xffff)); gf1 += bf2f((u16)(ihp1 >> 16));
                gg0 += bf2f((u16)(ihp2 & 0xffff)); gg1 += bf2f((u16)(ihp2 >> 16));
                go0 += bf2f((u16)(ihp3 & 0xffff)); go1 += bf2f((u16)(ihp3 >> 16));
            }
            float c20 = sigm(gf0) * cold.x + sigm(gi0) * tanhx(gg0);
            float c21 = sigm(gf1) * cold.y + sigm(gi1) * tanhx(gg1);
            float h20 = sigm(go0) * tanhx(c20);
            float h21 = sigm(go1) * tanhx(c21);
            *(float2*)(cbuf + eb * HH + ecol) = make_float2(c20, c21);
            unsigned hp = (unsigned)f2bf(h20) | ((unsigned)f2bf(h21) << 16);
            u16* ha = hbase + (size_t)(t + 1) * 32 * HH + (size_t)eb * HH + ecol;
            // agent-scope write-through: consumers on other XCDs read fresh
            __hip_atomic_store((unsigned*)ha, hp, __ATOMIC_RELAXED,
                               __HIP_MEMORY_SCOPE_AGENT);
        }
        asm volatile("s_waitcnt vmcnt(0)" ::: "memory");
        __syncthreads();   // all waves' h-stores drained & globally visible
        if (tid == 0)
            atomicAdd(f_self + t * 64 + tile, 1);   // RMW at coherence point
    }
}

__global__ __launch_bounds__(512) void recur_kernel(
    const u16* __restrict__ posW, const u16* __restrict__ w0W, const u16* __restrict__ w1W,
    const u16* __restrict__ posIH, const u16* __restrict__ w0IH,
    const float* __restrict__ w1bih, const float* __restrict__ w1bhh,
    u16* __restrict__ ph, u16* __restrict__ wh0, u16* __restrict__ wh1,
    float* __restrict__ c_pos, float* __restrict__ c_w0, float* __restrict__ c_w1,
    int* flags)
{
    __shared__ float lds_g[8][32][16];
    // flag layout: f[cell][t][wg] : flags + cell*8192 + t*64 + wg  (ints)
    int* f_pos = flags;
    int* f_w0  = flags + 8192;
    int* f_w1  = flags + 16384;
    const int blk = blockIdx.x;
    if (blk < 16)
        recur_cell<0, 256, 1024, 256, 1280>(posW, posIH, nullptr, nullptr,
            wh1, ph, ph, c_pos, f_pos, 16, f_w1, 64, blk, lds_g);
    else if (blk < 80)
        recur_cell<1, 1024, 256, 1024, 1280>(w0W, w0IH, nullptr, nullptr,
            ph, wh0, wh0, c_w0, f_w0, 64, f_pos, 16, blk - 16, lds_g);
    else
        recur_cell<2, 1024, 1024, 1024, 2048>(w1W, nullptr, w1bih, w1bhh,
            wh0, wh1, wh1, c_w1, f_w1, 64, f_w0, 64, blk - 80, lds_g);
}

// ---------------------------------------------------------------------------
// pos projection + log-softmax over 45 (unchanged)
// ---------------------------------------------------------------------------
__global__ __launch_bounds__(256) void posproj_kernel(
    const u16* __restrict__ ph, const float* __restrict__ W,
    const float* __restrict__ bias, float* __restrict__ out)
{
    __shared__ float w_lds[256 * 48 + 32];
    for (int i = threadIdx.x; i < 45 * 256; i += 256) {
        int j = i >> 8, k = i & 255;
        w_lds[k * 48 + j] = W[i];
    }
    __syncthreads();
    const int wv = threadIdx.x >> 6, lane = threadIdx.x & 63;
    const int row = blockIdx.x * 4 + wv;
    const int t = row >> 5, b = row & 31;
    const u16* x = ph + (size_t)(t + 1) * 8192 + b * 256;
    const int j = (lane < 45) ? lane : 0;
    float acc = 0.f;
    for (int k = 0; k < 256; k++) acc += bf2f(x[k]) * w_lds[k * 48 + j];
    float l = (lane < 45) ? (acc + bias[j]) : -INFINITY;
    float m = l;
    for (int mask = 1; mask < 64; mask <<= 1) m = fmaxf(m, __shfl_xor(m, mask));
    float e = (lane < 45) ? __expf(l - m) : 0.f;
    float s = e;
    for (int mask = 1; mask < 64; mask <<= 1) s += __shfl_xor(s, mask);
    if (lane < 45) out[(size_t)row * 45 + lane] = l - m - logf(s);
}

// ---------------------------------------------------------------------------
// word projection (unchanged)
// ---------------------------------------------------------------------------
__global__ __launch_bounds__(256) void wordproj_kernel(
    const u16* __restrict__ A, const u16* __restrict__ B,
    const float* __restrict__ bias, float* __restrict__ out,
    float* __restrict__ sumexp, int M, int N, int K)
{
    const int tid = threadIdx.x, w = tid >> 6, lane = tid & 63;
    const int quad = lane >> 4, lm = lane & 15;
    const int n0 = blockIdx.x * 64, m0 = blockIdx.y * 64 + w * 16;
    const u16* Ap = A + (size_t)(m0 + lm) * K + quad * 8;
    const u16* Bp = B + (size_t)(n0 + lm) * K + quad * 8;
    f4v acc[4] = {{0,0,0,0},{0,0,0,0},{0,0,0,0},{0,0,0,0}};
    for (int k = 0; k < K; k += 32) {
        s8v a = *(const s8v*)(Ap + k);
#pragma unroll
        for (int nt = 0; nt < 4; nt++) {
            s8v b = *(const s8v*)(Bp + (size_t)nt * 16 * K + k);
            acc[nt] = mfma16(a, b, acc[nt]);
        }
    }
    float se[4] = {0.f, 0.f, 0.f, 0.f};
#pragma unroll
    for (int nt = 0; nt < 4; nt++)
#pragma unroll
        for (int r = 0; r < 4; r++) {
            int col = n0 + nt * 16 + lm;
            int row = m0 + quad * 4 + r;
            float v = acc[nt][r] + bias[col];
            out[(size_t)row * N + col] = v;
            se[r] += __expf(v);
        }
#pragma unroll
    for (int r = 0; r < 4; r++) {
        float s = se[r];
        s += __shfl_xor(s, 1); s += __shfl_xor(s, 2);
        s += __shfl_xor(s, 4); s += __shfl_xor(s, 8);
        if (lm == 0) atomicAdd(&sumexp[m0 + quad * 4 + r], s);
    }
}

__global__ __launch_bounds__(256) void fixup_kernel(
    float* __restrict__ wout, const float* __restrict__ sumexp)
{
    const int row = blockIdx.x;
    const float lse = logf(sumexp[row]);
    float4* p = (float4*)(wout + (size_t)row * 32000);
    for (int i = threadIdx.x; i < 8000; i += 256) {
        float4 v = p[i];
        v.x -= lse; v.y -= lse; v.z -= lse; v.w -= lse;
        p[i] = v;
    }
}

__global__ __launch_bounds__(256) void fallback_zero(float* out, long long n) {
    for (long long i = (long long)blockIdx.x * 256 + threadIdx.x; i < n;
         i += (long long)gridDim.x * 256) out[i] = 0.f;
}

// ---------------------------------------------------------------------------
extern "C" void kernel_launch(void* const* d_in, const int* in_sizes, int n_in,
                              void* d_out, int out_size, void* d_ws, size_t ws_size,
                              hipStream_t stream)
{
    const int*   pos      = (const int*)  d_in[0];
    const int*   word     = (const int*)  d_in[1];
    const float* pos_emb  = (const float*)d_in[2];
    const float* word_emb = (const float*)d_in[3];
    const float* pWih     = (const float*)d_in[4];
    const float* pWhh     = (const float*)d_in[5];
    const float* pbih     = (const float*)d_in[6];
    const float* pbhh     = (const float*)d_in[7];
    const float* w0Wih    = (const float*)d_in[8];
    const float* w0Whh    = (const float*)d_in[9];
    const float* w0bih    = (const float*)d_in[10];
    const float* w0bhh    = (const float*)d_in[11];
    const float* w1Wih    = (const float*)d_in[12];
    const float* w1Whh    = (const float*)d_in[13];
    const float* w1bih    = (const float*)d_in[14];
    const float* w1bhh    = (const float*)d_in[15];
    const float* ppW      = (const float*)d_in[16];
    const float* ppb      = (const float*)d_in[17];
    const float* wp1W     = (const float*)d_in[18];
    const float* wp1b     = (const float*)d_in[19];
    const float* wp2b     = (const float*)d_in[20];

    char* ws = (char*)d_ws;
    size_t off = 0;
    auto alloc = [&](size_t bytes) -> size_t {
        size_t o = off; off = (off + bytes + 255) & ~(size_t)255; return o;
    };
    // --- zero-init region (one memset) ---
    size_t o_flags  = alloc(3 * 128 * 64 * 4);   // per-WG flag slots
    size_t o_sumexp = alloc(4096 * 4);
    size_t o_cpos   = alloc(32 * 256 * 4);
    size_t o_cw0    = alloc(32 * 1024 * 4);
    size_t o_cw1    = alloc(32 * 1024 * 4);
    size_t o_ph     = alloc((size_t)129 * 32 * 256 * 2);
    size_t o_wh0    = alloc((size_t)129 * 32 * 1024 * 2);
    size_t o_wh1    = alloc((size_t)129 * 32 * 1024 * 2);
    size_t zero_end = off;
    // --- rest ---
    size_t o_pemb   = alloc((size_t)4096 * 64 * 2);
    size_t o_wemb   = alloc((size_t)4096 * 512 * 2);
    size_t o_wembW  = alloc((size_t)32000 * 512 * 2);
    size_t o_wp1    = alloc((size_t)512 * 1024 * 2);
    size_t o_pWihA  = alloc((size_t)1024 * 64 * 2);
    size_t o_w0WihA = alloc((size_t)4096 * 512 * 2);
    size_t o_posW   = alloc((size_t)1024 * 1280 * 2);
    size_t o_w0W    = alloc((size_t)4096 * 1280 * 2);
    size_t o_w1W    = alloc((size_t)4096 * 2048 * 2);
    size_t o_posIH  = alloc((size_t)4096 * 1024 * 2);
    size_t o_w0IH   = alloc((size_t)4096 * 4096 * 2);
    size_t o_wmid   = alloc((size_t)4096 * 512 * 2);

    if (ws_size < off) {
        fallback_zero<<<2048, 256, 0, stream>>>((float*)d_out, (long long)out_size);
        return;
    }

    hipMemsetAsync(ws, 0, zero_end, stream);

    prep_kernel<<<2048, 256, 0, stream>>>(
        pos, word, pos_emb, word_emb, pWih, pWhh, w0Wih, w0Whh, w1Wih, w1Whh, wp1W,
        (u16*)(ws + o_pemb), (u16*)(ws + o_wemb), (u16*)(ws + o_wembW), (u16*)(ws + o_wp1),
        (u16*)(ws + o_pWihA), (u16*)(ws + o_w0WihA),
        (u16*)(ws + o_posW), (u16*)(ws + o_w0W), (u16*)(ws + o_w1W));

    // posIH = p_emb @ posWihA^T + pbih + pbhh   [4096,1024]
    gemm_bf16_kernel<<<dim3(16, 64), 256, 0, stream>>>(
        (u16*)(ws + o_pemb), (u16*)(ws + o_pWihA), pbih, pbhh,
        (u16*)(ws + o_posIH), 4096, 1024, 64);
    // w0IH = w_emb @ w0WihA^T + w0bih + w0bhh   [4096,4096]
    gemm_bf16_kernel<<<dim3(64, 64), 256, 0, stream>>>(
        (u16*)(ws + o_wemb), (u16*)(ws + o_w0WihA), w0bih, w0bhh,
        (u16*)(ws + o_w0IH), 4096, 4096, 512);

    recur_kernel<<<144, 512, 0, stream>>>(
        (u16*)(ws + o_posW), (u16*)(ws + o_w0W), (u16*)(ws + o_w1W),
        (u16*)(ws + o_posIH), (u16*)(ws + o_w0IH), w1bih, w1bhh,
        (u16*)(ws + o_ph), (u16*)(ws + o_wh0), (u16*)(ws + o_wh1),
        (float*)(ws + o_cpos), (float*)(ws + o_cw0), (float*)(ws + o_cw1),
        (int*)(ws + o_flags));

    // w_mid = wh1[1..128] @ wp1W^T + wp1b   [4096,512] bf16
    gemm_bf16_kernel<<<dim3(8, 64), 256, 0, stream>>>(
        (u16*)(ws + o_wh1) + 32 * 1024, (u16*)(ws + o_wp1), wp1b, nullptr,
        (u16*)(ws + o_wmid), 4096, 512, 1024);

    posproj_kernel<<<1024, 256, 0, stream>>>(
        (u16*)(ws + o_ph), ppW, ppb, (float*)d_out);

    wordproj_kernel<<<dim3(500, 64), 256, 0, stream>>>(
        (u16*)(ws + o_wmid), (u16*)(ws + o_wembW), wp2b,
        (float*)d_out + 184320, (float*)(ws + o_sumexp), 4096, 32000, 512);

    fixup_kernel<<<4096, 256, 0, stream>>>(
        (float*)d_out + 184320, (float*)(ws + o_sumexp));
}

// Round 4
// 5021.824 us; speedup vs baseline: 3.6467x; 1.3186x over previous
//
#include <hip/hip_runtime.h>
#include <hip/hip_bf16.h>

typedef unsigned short u16;
typedef short s8v __attribute__((ext_vector_type(8)));   // 8 bf16 in 4 VGPRs
typedef float f4v __attribute__((ext_vector_type(4)));   // MFMA accumulator

#define T_STEPS 128
#define BATCH 32

__device__ __forceinline__ float bf2f(u16 h) { return __uint_as_float(((unsigned)h) << 16); }
__device__ __forceinline__ u16 f2bf(float f) {
    unsigned u = __float_as_uint(f);
    unsigned r = u + 0x7fffu + ((u >> 16) & 1u);
    return (u16)(r >> 16);
}
__device__ __forceinline__ f4v mfma16(s8v a, s8v b, f4v c) {
    return __builtin_amdgcn_mfma_f32_16x16x32_bf16(a, b, c, 0, 0, 0);
}
__device__ __forceinline__ float sigm(float x) { return 1.f / (1.f + __expf(-x)); }
__device__ __forceinline__ float tanhx(float x) { return 1.f - 2.f / (1.f + __expf(2.f * x)); }

// ---------------------------------------------------------------------------
// prep: embedding gathers + bf16 weight packing (unchanged)
// ---------------------------------------------------------------------------
__global__ __launch_bounds__(256) void prep_kernel(
    const int* __restrict__ pos, const int* __restrict__ word,
    const float* __restrict__ pos_emb, const float* __restrict__ word_emb,
    const float* __restrict__ pWih, const float* __restrict__ pWhh,
    const float* __restrict__ w0Wih, const float* __restrict__ w0Whh,
    const float* __restrict__ w1Wih, const float* __restrict__ w1Whh,
    const float* __restrict__ wp1W,
    u16* __restrict__ p_emb_bf, u16* __restrict__ w_emb_bf,
    u16* __restrict__ word_emb_bf, u16* __restrict__ wp1W_bf,
    u16* __restrict__ posWihA, u16* __restrict__ w0WihA,
    u16* __restrict__ posW, u16* __restrict__ w0W, u16* __restrict__ w1W)
{
    const long long total = 36372480LL;
    for (long long i = (long long)blockIdx.x * 256 + threadIdx.x; i < total;
         i += (long long)gridDim.x * 256) {
        long long r = i;
        if (r < 262144) { int tb = (int)(r >> 6), e = (int)(r & 63);
            p_emb_bf[r] = f2bf(pos_emb[(size_t)pos[tb] * 64 + e]); continue; }
        r -= 262144;
        if (r < 2097152) { int tb = (int)(r >> 9), e = (int)(r & 511);
            w_emb_bf[r] = f2bf(word_emb[(size_t)word[tb] * 512 + e]); continue; }
        r -= 2097152;
        if (r < 16384000) { word_emb_bf[r] = f2bf(word_emb[r]); continue; }
        r -= 16384000;
        if (r < 524288) { wp1W_bf[r] = f2bf(wp1W[r]); continue; }
        r -= 524288;
        if (r < 65536) { int j = (int)(r >> 6), k = (int)(r & 63);
            posWihA[r] = f2bf(pWih[(size_t)j * 1088 + k]); continue; }
        r -= 65536;
        if (r < 2097152) { int j = (int)(r >> 9), k = (int)(r & 511);
            w0WihA[r] = f2bf(w0Wih[(size_t)j * 768 + k]); continue; }
        r -= 2097152;
        if (r < 1310720) { int j = (int)(r / 1280), c = (int)(r % 1280);
            posW[r] = f2bf(c < 1024 ? pWih[(size_t)j * 1088 + 64 + c]
                                    : pWhh[(size_t)j * 256 + (c - 1024)]); continue; }
        r -= 1310720;
        if (r < 5242880) { int j = (int)(r / 1280), c = (int)(r % 1280);
            w0W[r] = f2bf(c < 256 ? w0Wih[(size_t)j * 768 + 512 + c]
                                  : w0Whh[(size_t)j * 1024 + (c - 256)]); continue; }
        r -= 5242880;
        { int j = (int)(r >> 11), c = (int)(r & 2047);
          w1W[r] = f2bf(c < 1024 ? w1Wih[(size_t)j * 1024 + c]
                                 : w1Whh[(size_t)j * 1024 + (c - 1024)]); }
    }
}

// ---------------------------------------------------------------------------
// Generic bf16 GEMM (unchanged)
// ---------------------------------------------------------------------------
__global__ __launch_bounds__(256) void gemm_bf16_kernel(
    const u16* __restrict__ A, const u16* __restrict__ B,
    const float* __restrict__ bias1, const float* __restrict__ bias2,
    u16* __restrict__ out, int M, int N, int K)
{
    const int tid = threadIdx.x, w = tid >> 6, lane = tid & 63;
    const int quad = lane >> 4, lm = lane & 15;
    const int n0 = blockIdx.x * 64, m0 = blockIdx.y * 64 + w * 16;
    const u16* Ap = A + (size_t)(m0 + lm) * K + quad * 8;
    const u16* Bp = B + (size_t)(n0 + lm) * K + quad * 8;
    f4v acc[4] = {{0,0,0,0},{0,0,0,0},{0,0,0,0},{0,0,0,0}};
    for (int k = 0; k < K; k += 32) {
        s8v a = *(const s8v*)(Ap + k);
#pragma unroll
        for (int nt = 0; nt < 4; nt++) {
            s8v b = *(const s8v*)(Bp + (size_t)nt * 16 * K + k);
            acc[nt] = mfma16(a, b, acc[nt]);
        }
    }
#pragma unroll
    for (int nt = 0; nt < 4; nt++)
#pragma unroll
        for (int r = 0; r < 4; r++) {
            int col = n0 + nt * 16 + lm;
            int row = m0 + quad * 4 + r;
            float v = acc[nt][r];
            if (bias1) v += bias1[col];
            if (bias2) v += bias2[col];
            out[(size_t)row * N + col] = f2bf(v);
        }
}

// ---------------------------------------------------------------------------
// Persistent recurrence kernel, v5.
// v4 post-mortem: the 11 us/stage was serialized MALL-latency x-loads
// (write-through h data is in no consumer's L2; VGPR=36 allowed ~2 loads in
// flight -> 32 round trips/step). Fix: DMA-stage the x tiles into LDS with
// global_load_lds (queue depth independent of VGPRs; one vmcnt(0) drain),
// MFMA reads from LDS. Swizzle: LDS granule (r, c^(r&7)) via pre-swizzled
// global source (gload_lds writes linearly), same XOR on ds_read addresses
// -> uniform 8 lanes per 4-bank window = wave64 b128 floor.
// Weights stay in global (L2-resident) with an explicit rotate-4 register
// pipeline. One 64 KB LDS x-buffer reused by phase A then phase B (the
// B-wait barrier separates them). Sync machinery unchanged from v4 (proven).
// ---------------------------------------------------------------------------
__device__ __forceinline__ void waitwg(int* f, int n) {
    if (threadIdx.x < 64) {
        int* p = f + (threadIdx.x < (unsigned)n ? threadIdx.x : 0);
        int tries = 0;
        while (__hip_atomic_load(p, __ATOMIC_RELAXED, __HIP_MEMORY_SCOPE_AGENT) == 0) {
            __builtin_amdgcn_s_sleep(1);
            if (++tries > (1 << 19)) break;   // escape hatch: never hang
        }
    }
    __syncthreads();
    asm volatile("" ::: "memory");
}

// Stage a [32][L] bf16 tile into LDS with XOR-swizzled granules.
// LDS granule (r, cp) holds global granule (r, cp ^ (r&7)); 16B granules.
template<int L>
__device__ __forceinline__ void stage_x(u16* xb, const u16* xg) {
    constexpr int NC = L / 8;                  // 16B granules per row
    constexpr int ROUNDS = (32 * NC) / 512;    // L=1024 -> 8, L=256 -> 2
    const int tid = threadIdx.x;
    char* wdst = (char*)xb + ((tid >> 6) << 10);   // wave-uniform LDS base
#pragma unroll
    for (int rd = 0; rd < ROUNDS; rd++) {
        int G = rd * 512 + tid;
        int r = G / NC, cp = G % NC;
        int c = cp ^ (r & 7);                  // inverse swizzle on the SOURCE
        __builtin_amdgcn_global_load_lds(
            (const __attribute__((address_space(1))) void*)(xg + (size_t)r * L + (size_t)c * 8),
            (__attribute__((address_space(3))) void*)(wdst + rd * 8192),
            16, 0, 0);
    }
}

// One GEMM phase: acc += x(LDS, swizzled) @ W(global, rotate-4 pipelined)^T
template<int L>
__device__ __forceinline__ void gemm_phase(const u16* xb, const u16* Wp,
                                           int lm, int quad, int kh,
                                           f4v& m0, f4v& m1) {
    constexpr int NC = L / 8;
    constexpr int NI = L / 64;                 // per-wave k-iters (half of L)
    const int s = lm & 7;
    const char* xc = (const char*)xb;
    const int rb0 = lm * (NC * 16);
    const int rb1 = (lm + 16) * (NC * 16);
    const int cb = kh * (NC / 2);
    s8v bq[4];
#pragma unroll
    for (int i = 0; i < 4; i++) bq[i] = *(const s8v*)(Wp + i * 32);
#pragma unroll
    for (int i = 0; i < NI; i++) {
        int cx = ((cb + i * 4 + quad) ^ s) << 4;
        s8v a0 = *(const s8v*)(xc + rb0 + cx);
        s8v a1 = *(const s8v*)(xc + rb1 + cx);
        s8v bw = bq[i & 3];
        if (i + 4 < NI) bq[i & 3] = *(const s8v*)(Wp + (i + 4) * 32);
        m0 = mfma16(a0, bw, m0);
        m1 = mfma16(a1, bw, m1);
    }
}

template<int CELL, int HH, int L1, int L2, int RS>
__device__ __forceinline__ void recur_cell(
    const u16* __restrict__ W, const u16* __restrict__ IH,
    const float* __restrict__ bih, const float* __restrict__ bhh,
    const u16* __restrict__ x1base, const u16* __restrict__ x2base,
    u16* __restrict__ hbase, float* __restrict__ cbuf,
    int* f_self, int nself, int* f_prod, int nprod,
    int tile, float (&lds_g)[8][32][16], u16* xstage)
{
    const int tid = threadIdx.x, w = tid >> 6, lane = tid & 63;
    const int quad = lane >> 4, lm = lane & 15, g = w & 3, kh = w >> 2;
    const int n0 = tile * 16;
    const int row = g * HH + n0 + lm;
    const u16* WpB = W + (size_t)row * RS + quad * 8 + kh * (L1 / 2);
    const u16* WpA = W + (size_t)row * RS + quad * 8 + L1 + kh * (L2 / 2);
    // elementwise: threads 0..255, 2 adjacent cols each
    const int eb = tid >> 3, ec = (tid & 7) * 2, ecol = n0 + ec;

    // CELL2 gate biases are t-invariant: hoist out of the loop
    float bi0=0, bi1=0, bf0=0, bf1=0, bg0=0, bg1=0, bo0=0, bo1=0;
    if (CELL == 2 && tid < 256) {
        bi0 = bih[ecol]        + bhh[ecol];
        bi1 = bih[ecol+1]      + bhh[ecol+1];
        bf0 = bih[1024+ecol]   + bhh[1024+ecol];
        bf1 = bih[1024+ecol+1] + bhh[1024+ecol+1];
        bg0 = bih[2048+ecol]   + bhh[2048+ecol];
        bg1 = bih[2048+ecol+1] + bhh[2048+ecol+1];
        bo0 = bih[3072+ecol]   + bhh[3072+ecol];
        bo1 = bih[3072+ecol+1] + bhh[3072+ecol+1];
    }

    for (int t = 0; t < T_STEPS; t++) {
        // A-wait: own cell finished step t-1 (normally already satisfied)
        if (t > 0) waitwg(f_self + (t - 1) * 64, nself);

        // stage x2 (own-history input) into LDS, then phase A
        stage_x<L2>(xstage, x2base + (size_t)t * 32 * L2);
        asm volatile("s_waitcnt vmcnt(0)" ::: "memory");
        __syncthreads();
        f4v am0 = {0,0,0,0}, am1 = {0,0,0,0};
        gemm_phase<L2>(xstage, WpA, lm, quad, kh, am0, am1);

        // prefetch elementwise inputs (IH gates, c-state) under the wait
        unsigned ihp0=0, ihp1=0, ihp2=0, ihp3=0;
        float2 cold = {0.f, 0.f};
        if (tid < 256) {
            if constexpr (CELL == 0) {
                const u16* ih = IH + (size_t)(t * 32 + eb) * 1024 + ecol;
                ihp0 = *(const unsigned*)(ih);
                ihp1 = *(const unsigned*)(ih + 256);
                ihp2 = *(const unsigned*)(ih + 512);
                ihp3 = *(const unsigned*)(ih + 768);
            } else if constexpr (CELL == 1) {
                const u16* ih = IH + (size_t)(t * 32 + eb) * 4096 + ecol;
                ihp0 = *(const unsigned*)(ih);
                ihp1 = *(const unsigned*)(ih + 1024);
                ihp2 = *(const unsigned*)(ih + 2048);
                ihp3 = *(const unsigned*)(ih + 3072);
            }
            cold = *(const float2*)(cbuf + eb * HH + ecol);
        }
        asm volatile("" ::: "memory");

        // B-wait: direct producer (THE critical-path wait). Always barrier:
        // it also separates phase-A LDS reads from the phase-B stage writes.
        if (!(CELL == 0 && t == 0))
            waitwg(f_prod + (CELL == 0 ? (t - 1) : t) * 64, nprod);
        else
            __syncthreads();

        // stage x1 (just-produced input) into LDS, then phase B
        const int t1 = (CELL == 0) ? t : t + 1;
        stage_x<L1>(xstage, x1base + (size_t)t1 * 32 * L1);
        asm volatile("s_waitcnt vmcnt(0)" ::: "memory");
        __syncthreads();
        gemm_phase<L1>(xstage, WpB, lm, quad, kh, am0, am1);

        // gate partials -> LDS (wave w = gate g, K-half kh)
#pragma unroll
        for (int r = 0; r < 4; r++) {
            lds_g[w][quad * 4 + r][lm]      = am0[r];
            lds_g[w][16 + quad * 4 + r][lm] = am1[r];
        }
        __syncthreads();

        // elementwise LSTM update: 2 adjacent (eb, col) elements per thread
        if (tid < 256) {
            float2 pI = *(const float2*)&lds_g[0][eb][ec];
            float2 pF = *(const float2*)&lds_g[1][eb][ec];
            float2 pG = *(const float2*)&lds_g[2][eb][ec];
            float2 pO = *(const float2*)&lds_g[3][eb][ec];
            float2 qI = *(const float2*)&lds_g[4][eb][ec];
            float2 qF = *(const float2*)&lds_g[5][eb][ec];
            float2 qG = *(const float2*)&lds_g[6][eb][ec];
            float2 qO = *(const float2*)&lds_g[7][eb][ec];
            float gi0 = pI.x + qI.x, gi1 = pI.y + qI.y;
            float gf0 = pF.x + qF.x, gf1 = pF.y + qF.y;
            float gg0 = pG.x + qG.x, gg1 = pG.y + qG.y;
            float go0 = pO.x + qO.x, go1 = pO.y + qO.y;
            if constexpr (CELL == 2) {
                gi0 += bi0; gi1 += bi1; gf0 += bf0; gf1 += bf1;
                gg0 += bg0; gg1 += bg1; go0 += bo0; go1 += bo1;
            } else {
                gi0 += bf2f((u16)(ihp0 & 0xffff)); gi1 += bf2f((u16)(ihp0 >> 16));
                gf0 += bf2f((u16)(ihp1 & 0xffff)); gf1 += bf2f((u16)(ihp1 >> 16));
                gg0 += bf2f((u16)(ihp2 & 0xffff)); gg1 += bf2f((u16)(ihp2 >> 16));
                go0 += bf2f((u16)(ihp3 & 0xffff)); go1 += bf2f((u16)(ihp3 >> 16));
            }
            float c20 = sigm(gf0) * cold.x + sigm(gi0) * tanhx(gg0);
            float c21 = sigm(gf1) * cold.y + sigm(gi1) * tanhx(gg1);
            float h20 = sigm(go0) * tanhx(c20);
            float h21 = sigm(go1) * tanhx(c21);
            *(float2*)(cbuf + eb * HH + ecol) = make_float2(c20, c21);
            unsigned hp = (unsigned)f2bf(h20) | ((unsigned)f2bf(h21) << 16);
            u16* ha = hbase + (size_t)(t + 1) * 32 * HH + (size_t)eb * HH + ecol;
            // agent-scope write-through: consumers on other XCDs read fresh
            __hip_atomic_store((unsigned*)ha, hp, __ATOMIC_RELAXED,
                               __HIP_MEMORY_SCOPE_AGENT);
        }
        asm volatile("s_waitcnt vmcnt(0)" ::: "memory");
        __syncthreads();   // all waves' h-stores drained & globally visible
        if (tid == 0)
            atomicAdd(f_self + t * 64 + tile, 1);   // RMW at coherence point
    }
}

__global__ __launch_bounds__(512) void recur_kernel(
    const u16* __restrict__ posW, const u16* __restrict__ w0W, const u16* __restrict__ w1W,
    const u16* __restrict__ posIH, const u16* __restrict__ w0IH,
    const float* __restrict__ w1bih, const float* __restrict__ w1bhh,
    u16* __restrict__ ph, u16* __restrict__ wh0, u16* __restrict__ wh1,
    float* __restrict__ c_pos, float* __restrict__ c_w0, float* __restrict__ c_w1,
    int* flags)
{
    __shared__ __align__(16) float lds_g[8][32][16];
    __shared__ __align__(16) u16 xstage[32 * 1024];   // 64 KB x-tile buffer
    // flag layout: f[cell][t][wg] : flags + cell*8192 + t*64 + wg  (ints)
    int* f_pos = flags;
    int* f_w0  = flags + 8192;
    int* f_w1  = flags + 16384;
    const int blk = blockIdx.x;
    if (blk < 16)
        recur_cell<0, 256, 1024, 256, 1280>(posW, posIH, nullptr, nullptr,
            wh1, ph, ph, c_pos, f_pos, 16, f_w1, 64, blk, lds_g, xstage);
    else if (blk < 80)
        recur_cell<1, 1024, 256, 1024, 1280>(w0W, w0IH, nullptr, nullptr,
            ph, wh0, wh0, c_w0, f_w0, 64, f_pos, 16, blk - 16, lds_g, xstage);
    else
        recur_cell<2, 1024, 1024, 1024, 2048>(w1W, nullptr, w1bih, w1bhh,
            wh0, wh1, wh1, c_w1, f_w1, 64, f_w0, 64, blk - 80, lds_g, xstage);
}

// ---------------------------------------------------------------------------
// pos projection + log-softmax over 45 (unchanged)
// ---------------------------------------------------------------------------
__global__ __launch_bounds__(256) void posproj_kernel(
    const u16* __restrict__ ph, const float* __restrict__ W,
    const float* __restrict__ bias, float* __restrict__ out)
{
    __shared__ float w_lds[256 * 48 + 32];
    for (int i = threadIdx.x; i < 45 * 256; i += 256) {
        int j = i >> 8, k = i & 255;
        w_lds[k * 48 + j] = W[i];
    }
    __syncthreads();
    const int wv = threadIdx.x >> 6, lane = threadIdx.x & 63;
    const int row = blockIdx.x * 4 + wv;
    const int t = row >> 5, b = row & 31;
    const u16* x = ph + (size_t)(t + 1) * 8192 + b * 256;
    const int j = (lane < 45) ? lane : 0;
    float acc = 0.f;
    for (int k = 0; k < 256; k++) acc += bf2f(x[k]) * w_lds[k * 48 + j];
    float l = (lane < 45) ? (acc + bias[j]) : -INFINITY;
    float m = l;
    for (int mask = 1; mask < 64; mask <<= 1) m = fmaxf(m, __shfl_xor(m, mask));
    float e = (lane < 45) ? __expf(l - m) : 0.f;
    float s = e;
    for (int mask = 1; mask < 64; mask <<= 1) s += __shfl_xor(s, mask);
    if (lane < 45) out[(size_t)row * 45 + lane] = l - m - logf(s);
}

// ---------------------------------------------------------------------------
// word projection (unchanged)
// ---------------------------------------------------------------------------
__global__ __launch_bounds__(256) void wordproj_kernel(
    const u16* __restrict__ A, const u16* __restrict__ B,
    const float* __restrict__ bias, float* __restrict__ out,
    float* __restrict__ sumexp, int M, int N, int K)
{
    const int tid = threadIdx.x, w = tid >> 6, lane = tid & 63;
    const int quad = lane >> 4, lm = lane & 15;
    const int n0 = blockIdx.x * 64, m0 = blockIdx.y * 64 + w * 16;
    const u16* Ap = A + (size_t)(m0 + lm) * K + quad * 8;
    const u16* Bp = B + (size_t)(n0 + lm) * K + quad * 8;
    f4v acc[4] = {{0,0,0,0},{0,0,0,0},{0,0,0,0},{0,0,0,0}};
    for (int k = 0; k < K; k += 32) {
        s8v a = *(const s8v*)(Ap + k);
#pragma unroll
        for (int nt = 0; nt < 4; nt++) {
            s8v b = *(const s8v*)(Bp + (size_t)nt * 16 * K + k);
            acc[nt] = mfma16(a, b, acc[nt]);
        }
    }
    float se[4] = {0.f, 0.f, 0.f, 0.f};
#pragma unroll
    for (int nt = 0; nt < 4; nt++)
#pragma unroll
        for (int r = 0; r < 4; r++) {
            int col = n0 + nt * 16 + lm;
            int row = m0 + quad * 4 + r;
            float v = acc[nt][r] + bias[col];
            out[(size_t)row * N + col] = v;
            se[r] += __expf(v);
        }
#pragma unroll
    for (int r = 0; r < 4; r++) {
        float s = se[r];
        s += __shfl_xor(s, 1); s += __shfl_xor(s, 2);
        s += __shfl_xor(s, 4); s += __shfl_xor(s, 8);
        if (lm == 0) atomicAdd(&sumexp[m0 + quad * 4 + r], s);
    }
}

__global__ __launch_bounds__(256) void fixup_kernel(
    float* __restrict__ wout, const float* __restrict__ sumexp)
{
    const int row = blockIdx.x;
    const float lse = logf(sumexp[row]);
    float4* p = (float4*)(wout + (size_t)row * 32000);
    for (int i = threadIdx.x; i < 8000; i += 256) {
        float4 v = p[i];
        v.x -= lse; v.y -= lse; v.z -= lse; v.w -= lse;
        p[i] = v;
    }
}

__global__ __launch_bounds__(256) void fallback_zero(float* out, long long n) {
    for (long long i = (long long)blockIdx.x * 256 + threadIdx.x; i < n;
         i += (long long)gridDim.x * 256) out[i] = 0.f;
}

// ---------------------------------------------------------------------------
extern "C" void kernel_launch(void* const* d_in, const int* in_sizes, int n_in,
                              void* d_out, int out_size, void* d_ws, size_t ws_size,
                              hipStream_t stream)
{
    const int*   pos      = (const int*)  d_in[0];
    const int*   word     = (const int*)  d_in[1];
    const float* pos_emb  = (const float*)d_in[2];
    const float* word_emb = (const float*)d_in[3];
    const float* pWih     = (const float*)d_in[4];
    const float* pWhh     = (const float*)d_in[5];
    const float* pbih     = (const float*)d_in[6];
    const float* pbhh     = (const float*)d_in[7];
    const float* w0Wih    = (const float*)d_in[8];
    const float* w0Whh    = (const float*)d_in[9];
    const float* w0bih    = (const float*)d_in[10];
    const float* w0bhh    = (const float*)d_in[11];
    const float* w1Wih    = (const float*)d_in[12];
    const float* w1Whh    = (const float*)d_in[13];
    const float* w1bih    = (const float*)d_in[14];
    const float* w1bhh    = (const float*)d_in[15];
    const float* ppW      = (const float*)d_in[16];
    const float* ppb      = (const float*)d_in[17];
    const float* wp1W     = (const float*)d_in[18];
    const float* wp1b     = (const float*)d_in[19];
    const float* wp2b     = (const float*)d_in[20];

    char* ws = (char*)d_ws;
    size_t off = 0;
    auto alloc = [&](size_t bytes) -> size_t {
        size_t o = off; off = (off + bytes + 255) & ~(size_t)255; return o;
    };
    // --- zero-init region (one memset) ---
    size_t o_flags  = alloc(3 * 128 * 64 * 4);   // per-WG flag slots
    size_t o_sumexp = alloc(4096 * 4);
    size_t o_cpos   = alloc(32 * 256 * 4);
    size_t o_cw0    = alloc(32 * 1024 * 4);
    size_t o_cw1    = alloc(32 * 1024 * 4);
    size_t o_ph     = alloc((size_t)129 * 32 * 256 * 2);
    size_t o_wh0    = alloc((size_t)129 * 32 * 1024 * 2);
    size_t o_wh1    = alloc((size_t)129 * 32 * 1024 * 2);
    size_t zero_end = off;
    // --- rest ---
    size_t o_pemb   = alloc((size_t)4096 * 64 * 2);
    size_t o_wemb   = alloc((size_t)4096 * 512 * 2);
    size_t o_wembW  = alloc((size_t)32000 * 512 * 2);
    size_t o_wp1    = alloc((size_t)512 * 1024 * 2);
    size_t o_pWihA  = alloc((size_t)1024 * 64 * 2);
    size_t o_w0WihA = alloc((size_t)4096 * 512 * 2);
    size_t o_posW   = alloc((size_t)1024 * 1280 * 2);
    size_t o_w0W    = alloc((size_t)4096 * 1280 * 2);
    size_t o_w1W    = alloc((size_t)4096 * 2048 * 2);
    size_t o_posIH  = alloc((size_t)4096 * 1024 * 2);
    size_t o_w0IH   = alloc((size_t)4096 * 4096 * 2);
    size_t o_wmid   = alloc((size_t)4096 * 512 * 2);

    if (ws_size < off) {
        fallback_zero<<<2048, 256, 0, stream>>>((float*)d_out, (long long)out_size);
        return;
    }

    hipMemsetAsync(ws, 0, zero_end, stream);

    prep_kernel<<<2048, 256, 0, stream>>>(
        pos, word, pos_emb, word_emb, pWih, pWhh, w0Wih, w0Whh, w1Wih, w1Whh, wp1W,
        (u16*)(ws + o_pemb), (u16*)(ws + o_wemb), (u16*)(ws + o_wembW), (u16*)(ws + o_wp1),
        (u16*)(ws + o_pWihA), (u16*)(ws + o_w0WihA),
        (u16*)(ws + o_posW), (u16*)(ws + o_w0W), (u16*)(ws + o_w1W));

    // posIH = p_emb @ posWihA^T + pbih + pbhh   [4096,1024]
    gemm_bf16_kernel<<<dim3(16, 64), 256, 0, stream>>>(
        (u16*)(ws + o_pemb), (u16*)(ws + o_pWihA), pbih, pbhh,
        (u16*)(ws + o_posIH), 4096, 1024, 64);
    // w0IH = w_emb @ w0WihA^T + w0bih + w0bhh   [4096,4096]
    gemm_bf16_kernel<<<dim3(64, 64), 256, 0, stream>>>(
        (u16*)(ws + o_wemb), (u16*)(ws + o_w0WihA), w0bih, w0bhh,
        (u16*)(ws + o_w0IH), 4096, 4096, 512);

    recur_kernel<<<144, 512, 0, stream>>>(
        (u16*)(ws + o_posW), (u16*)(ws + o_w0W), (u16*)(ws + o_w1W),
        (u16*)(ws + o_posIH), (u16*)(ws + o_w0IH), w1bih, w1bhh,
        (u16*)(ws + o_ph), (u16*)(ws + o_wh0), (u16*)(ws + o_wh1),
        (float*)(ws + o_cpos), (float*)(ws + o_cw0), (float*)(ws + o_cw1),
        (int*)(ws + o_flags));

    // w_mid = wh1[1..128] @ wp1W^T + wp1b   [4096,512] bf16
    gemm_bf16_kernel<<<dim3(8, 64), 256, 0, stream>>>(
        (u16*)(ws + o_wh1) + 32 * 1024, (u16*)(ws + o_wp1), wp1b, nullptr,
        (u16*)(ws + o_wmid), 4096, 512, 1024);

    posproj_kernel<<<1024, 256, 0, stream>>>(
        (u16*)(ws + o_ph), ppW, ppb, (float*)d_out);

    wordproj_kernel<<<dim3(500, 64), 256, 0, stream>>>(
        (u16*)(ws + o_wmid), (u16*)(ws + o_wembW), wp2b,
        (float*)d_out + 184320, (float*)(ws + o_sumexp), 4096, 32000, 512);

    fixup_kernel<<<4096, 256, 0, stream>>>(
        (float*)d_out + 184320, (float*)(ws + o_sumexp));
}